// Round 3
// baseline (777.779 us; speedup 1.0000x reference)
//
#include <hip/hip_runtime.h>

#define DIM 128
#define NEG 0.2f
#define CAP 128   // per-node LDS alpha slots; degrees are ~Poisson(16), P(deg>128)~0

__device__ __forceinline__ float lrelu(float v) { return v > 0.f ? v : NEG * v; }

// ------------- GEMM + fused attention logits: H = X@W, al = H@a_src, ar = H@a_dst
__global__ __launch_bounds__(256) void gemm128_fused(const float* __restrict__ X,
                                                     const float* __restrict__ W,
                                                     const float* __restrict__ asrc,
                                                     const float* __restrict__ adst,
                                                     float* __restrict__ H,
                                                     float* __restrict__ al,
                                                     float* __restrict__ ar, int N) {
    __shared__ float sx[64 * 128];
    const int t = threadIdx.x;
    const int r0g = blockIdx.x * 64;
    const int remRows = N - r0g;

    const float4* X4 = (const float4*)(X + (size_t)r0g * DIM);
    float4* sx4 = (float4*)sx;
#pragma unroll
    for (int i = 0; i < 8; ++i) {
        int f = t + i * 256;
        int row = f >> 5;
        float4 v = make_float4(0.f, 0.f, 0.f, 0.f);
        if (row < remRows) v = X4[f];
        sx4[f] = v;
    }
    __syncthreads();

    const int c0 = (t & 31) * 4;
    const int rg = (t >> 5) * 8;
    float acc[8][4];
#pragma unroll
    for (int i = 0; i < 8; ++i)
#pragma unroll
        for (int j = 0; j < 4; ++j) acc[i][j] = 0.f;

    const float* Wp = W + c0;
    for (int k = 0; k < 128; k += 4) {
        float4 w0 = *(const float4*)(Wp + (k + 0) * DIM);
        float4 w1 = *(const float4*)(Wp + (k + 1) * DIM);
        float4 w2 = *(const float4*)(Wp + (k + 2) * DIM);
        float4 w3 = *(const float4*)(Wp + (k + 3) * DIM);
#pragma unroll
        for (int i = 0; i < 8; ++i) {
            float4 a = *(const float4*)(sx + (rg + i) * 128 + k);
            acc[i][0] += a.x * w0.x; acc[i][1] += a.x * w0.y; acc[i][2] += a.x * w0.z; acc[i][3] += a.x * w0.w;
            acc[i][0] += a.y * w1.x; acc[i][1] += a.y * w1.y; acc[i][2] += a.y * w1.z; acc[i][3] += a.y * w1.w;
            acc[i][0] += a.z * w2.x; acc[i][1] += a.z * w2.y; acc[i][2] += a.z * w2.z; acc[i][3] += a.z * w2.w;
            acc[i][0] += a.w * w3.x; acc[i][1] += a.w * w3.y; acc[i][2] += a.w * w3.z; acc[i][3] += a.w * w3.w;
        }
    }

#pragma unroll
    for (int i = 0; i < 8; ++i) {
        int row = rg + i;
        if (row < remRows) {
            float4 o = make_float4(acc[i][0], acc[i][1], acc[i][2], acc[i][3]);
            *(float4*)(H + (size_t)(r0g + row) * DIM + c0) = o;
        }
    }

    // fused epilogue: al/ar via half-wave reduction
    float4 av = *(const float4*)(asrc + c0);
    float4 dv = *(const float4*)(adst + c0);
    float pa[8], pr[8];
#pragma unroll
    for (int i = 0; i < 8; ++i) {
        pa[i] = acc[i][0] * av.x + acc[i][1] * av.y + acc[i][2] * av.z + acc[i][3] * av.w;
        pr[i] = acc[i][0] * dv.x + acc[i][1] * dv.y + acc[i][2] * dv.z + acc[i][3] * dv.w;
    }
#pragma unroll
    for (int off = 16; off; off >>= 1) {
#pragma unroll
        for (int i = 0; i < 8; ++i) {
            pa[i] += __shfl_xor(pa[i], off);
            pr[i] += __shfl_xor(pr[i], off);
        }
    }
    if ((t & 31) == 0) {
#pragma unroll
        for (int i = 0; i < 8; ++i) {
            int row = rg + i;
            if (row < remRows) {
                al[r0g + row] = pa[i];
                ar[r0g + row] = pr[i];
            }
        }
    }
}

// ---------------- combined CSR build (both edge sets as a 2N virtual graph) ----
__global__ void hist2_kernel(const int* __restrict__ ei, const int* __restrict__ eix,
                             int* __restrict__ cnt, int E1, int E2, int N) {
    int e = blockIdx.x * blockDim.x + threadIdx.x;
    if (e < E1) {
        atomicAdd(&cnt[ei[E1 + e]], 1);
    } else if (e < E1 + E2) {
        int k = e - E1;
        atomicAdd(&cnt[N + eix[E2 + k]], 1);
    }
}

__global__ __launch_bounds__(1024) void block_sum_kernel(const int* __restrict__ cnt,
                                                         int* __restrict__ bsum, int Ntot) {
    __shared__ int wsum[16];
    int t = threadIdx.x, wave = t >> 6, lane = t & 63;
    int i = blockIdx.x * 1024 + t;
    int v = (i < Ntot) ? cnt[i] : 0;
#pragma unroll
    for (int off = 32; off; off >>= 1) v += __shfl_xor(v, off);
    if (lane == 0) wsum[wave] = v;
    __syncthreads();
    if (t == 0) {
        int s = 0;
#pragma unroll
        for (int j = 0; j < 16; ++j) s += wsum[j];
        bsum[blockIdx.x] = s;
    }
}

// scans up to 128 block sums (2 waves)
__global__ __launch_bounds__(128) void scan_bsums_kernel(int* __restrict__ bsum, int nb,
                                                         int* __restrict__ row_off, int Ntot) {
    __shared__ int w0tot;
    int t = threadIdx.x;
    int v = (t < nb) ? bsum[t] : 0;
    int s = v;
#pragma unroll
    for (int off = 1; off < 64; off <<= 1) {
        int u = __shfl_up(s, off);
        if ((t & 63) >= off) s += u;
    }
    if (t == 63) w0tot = s;
    __syncthreads();
    if (t >= 64) s += w0tot;
    if (t < nb) bsum[t] = s - v;    // exclusive
    if (t == 127) row_off[Ntot] = s; // grand total
}

__global__ __launch_bounds__(1024) void block_scan_kernel(const int* __restrict__ cnt,
                                                          const int* __restrict__ bsum,
                                                          int* __restrict__ row_off,
                                                          int* __restrict__ cursor, int Ntot) {
    __shared__ int wsum[16];
    __shared__ int woff[16];
    int t = threadIdx.x, wave = t >> 6, lane = t & 63;
    int i = blockIdx.x * 1024 + t;
    int v = (i < Ntot) ? cnt[i] : 0;
    int s = v;
#pragma unroll
    for (int off = 1; off < 64; off <<= 1) {
        int u = __shfl_up(s, off);
        if (lane >= off) s += u;
    }
    if (lane == 63) wsum[wave] = s;
    __syncthreads();
    if (t == 0) {
        int r = 0;
#pragma unroll
        for (int j = 0; j < 16; ++j) { woff[j] = r; r += wsum[j]; }
    }
    __syncthreads();
    if (i < Ntot) {
        int excl = bsum[blockIdx.x] + woff[wave] + s - v;
        row_off[i] = excl;
        cursor[i] = excl;
    }
}

__global__ void scatter2_kernel(const int* __restrict__ ei, const int* __restrict__ eix,
                                int* __restrict__ cursor, int* __restrict__ col,
                                int E1, int E2, int N) {
    int e = blockIdx.x * blockDim.x + threadIdx.x;
    if (e < E1) {
        int d = ei[E1 + e];
        int p = atomicAdd(&cursor[d], 1);
        col[p] = ei[e];
    } else if (e < E1 + E2) {
        int k = e - E1;
        int d = N + eix[E2 + k];
        int p = atomicAdd(&cursor[d], 1);
        col[p] = eix[k];
    }
}

// ---------------- fused softmax-by-dst + aggregation, one wave per node -----
// Phase A: online softmax, stashing raw logits v in LDS (CAP slots/node),
//          then converting in place to alpha = exp(v-m)/s.
// Phase B: 2 half-waves x unroll 4 -> 8 independent 512B row loads in flight,
//          inner loop has NO exp and NO al[] gather.
__global__ __launch_bounds__(256) void agg_kernel(const float* __restrict__ H,
                                                  const float* __restrict__ al,
                                                  const float* __restrict__ ar,
                                                  const int* __restrict__ row_off,
                                                  const int* __restrict__ col,
                                                  const float* __restrict__ bias,
                                                  float* __restrict__ out, int N, int relu) {
    __shared__ float salpha[4][CAP];
    const int wv = threadIdx.x >> 6;
    const int w = blockIdx.x * 4 + wv;
    const int lane = threadIdx.x & 63;
    if (w >= N) return;

    const int beg = row_off[w];
    const int deg = row_off[w + 1] - beg;
    const float arn = ar[w];
    const float vself = lrelu(al[w] + arn);

    // ---- phase A: online segment softmax, logits -> LDS ----
    float mm = -1e30f, ss = 0.f;
    for (int i = lane; i < deg; i += 64) {
        float v = lrelu(al[col[beg + i]] + arn);
        if (i < CAP) salpha[wv][i] = v;
        float nm = fmaxf(mm, v);
        ss = ss * __expf(mm - nm) + __expf(v - nm);
        mm = nm;
    }
#pragma unroll
    for (int off = 32; off; off >>= 1) {
        float mo = __shfl_xor(mm, off);
        float so = __shfl_xor(ss, off);
        float nm = fmaxf(mm, mo);
        ss = ss * __expf(mm - nm) + so * __expf(mo - nm);
        mm = nm;
    }
    {   // merge self-loop
        float nm = fmaxf(mm, vself);
        ss = ss * __expf(mm - nm) + __expf(vself - nm);
        mm = nm;
    }
    const float m = mm;
    const float invs = 1.f / ss;

    // convert stashed logits to alphas (each lane rewrites its own slots)
    const int capdeg = deg < CAP ? deg : CAP;
    for (int i = lane; i < capdeg; i += 64)
        salpha[wv][i] = __expf(salpha[wv][i] - m) * invs;
    // same-wave LDS ops complete in order; cross-lane reads below see these writes

    // ---- phase B: weighted aggregation ----
    const int half = lane >> 5;
    const int l32 = lane & 31;
    const float aself = __expf(vself - m) * invs;
    const float4 hs = *(const float4*)(H + (size_t)w * DIM + 4 * l32);
    float4 acc = make_float4(0.f, 0.f, 0.f, 0.f);
    if (half == 0) {
        acc.x = aself * hs.x; acc.y = aself * hs.y;
        acc.z = aself * hs.z; acc.w = aself * hs.w;
    }

    int i = half;
    for (; i + 6 < deg; i += 8) {
        const int e = beg + i;
        int sn0 = col[e];
        int sn1 = col[e + 2];
        int sn2 = col[e + 4];
        int sn3 = col[e + 6];
        float a0, a1, a2, a3;
        if (i + 6 < CAP) {
            a0 = salpha[wv][i];     a1 = salpha[wv][i + 2];
            a2 = salpha[wv][i + 4]; a3 = salpha[wv][i + 6];
        } else {  // correctness fallback, never taken for Poisson(16) degrees
            a0 = __expf(lrelu(al[sn0] + arn) - m) * invs;
            a1 = __expf(lrelu(al[sn1] + arn) - m) * invs;
            a2 = __expf(lrelu(al[sn2] + arn) - m) * invs;
            a3 = __expf(lrelu(al[sn3] + arn) - m) * invs;
        }
        const float4 h0 = *(const float4*)(H + (size_t)sn0 * DIM + 4 * l32);
        const float4 h1 = *(const float4*)(H + (size_t)sn1 * DIM + 4 * l32);
        const float4 h2 = *(const float4*)(H + (size_t)sn2 * DIM + 4 * l32);
        const float4 h3 = *(const float4*)(H + (size_t)sn3 * DIM + 4 * l32);
        acc.x += a0 * h0.x + a1 * h1.x + a2 * h2.x + a3 * h3.x;
        acc.y += a0 * h0.y + a1 * h1.y + a2 * h2.y + a3 * h3.y;
        acc.z += a0 * h0.z + a1 * h1.z + a2 * h2.z + a3 * h3.z;
        acc.w += a0 * h0.w + a1 * h1.w + a2 * h2.w + a3 * h3.w;
    }
    for (; i < deg; i += 2) {
        int sn = col[beg + i];
        float a = (i < CAP) ? salpha[wv][i]
                            : __expf(lrelu(al[sn] + arn) - m) * invs;
        const float4 hv = *(const float4*)(H + (size_t)sn * DIM + 4 * l32);
        acc.x += a * hv.x; acc.y += a * hv.y;
        acc.z += a * hv.z; acc.w += a * hv.w;
    }

    // combine halves
    acc.x += __shfl_xor(acc.x, 32);
    acc.y += __shfl_xor(acc.y, 32);
    acc.z += __shfl_xor(acc.z, 32);
    acc.w += __shfl_xor(acc.w, 32);

    if (half == 0) {
        float4 b = *(const float4*)(bias + 4 * l32);
        float4 o = make_float4(acc.x + b.x, acc.y + b.y, acc.z + b.z, acc.w + b.w);
        if (relu) {
            o.x = fmaxf(o.x, 0.f); o.y = fmaxf(o.y, 0.f);
            o.z = fmaxf(o.z, 0.f); o.w = fmaxf(o.w, 0.f);
        }
        *(float4*)(out + (size_t)w * DIM + 4 * l32) = o;
    }
}

// ---------------- host-side launch ----------------
extern "C" void kernel_launch(void* const* d_in, const int* in_sizes, int n_in,
                              void* d_out, int out_size, void* d_ws, size_t ws_size,
                              hipStream_t stream) {
    const float* x = (const float*)d_in[0];
    const float* W[5];
    const float* asv[5];
    const float* adv[5];
    const float* bv[5];
    for (int i = 0; i < 5; ++i) {
        W[i]   = (const float*)d_in[1 + 4 * i];
        asv[i] = (const float*)d_in[2 + 4 * i];
        adv[i] = (const float*)d_in[3 + 4 * i];
        bv[i]  = (const float*)d_in[4 + 4 * i];
    }
    const int* ei  = (const int*)d_in[21];
    const int* eix = (const int*)d_in[22];
    const int N  = in_sizes[0] / DIM;
    const int E1 = in_sizes[21] / 2;
    const int E2 = in_sizes[22] / 2;
    const int Ntot = 2 * N;
    const int Etot = E1 + E2;

    size_t off = 0;
    auto alloc = [&](size_t bytes) {
        void* r = (char*)d_ws + off;
        off += (bytes + 255) & ~(size_t)255;
        return r;
    };
    float* Hbuf = (float*)alloc((size_t)N * DIM * sizeof(float));
    float* al   = (float*)alloc((size_t)N * sizeof(float));
    float* ar   = (float*)alloc((size_t)N * sizeof(float));
    int* cnt    = (int*)alloc((size_t)Ntot * sizeof(int));
    int* cur    = (int*)alloc((size_t)Ntot * sizeof(int));
    int* bsum   = (int*)alloc(128 * sizeof(int));
    int* row    = (int*)alloc((size_t)(Ntot + 1) * sizeof(int));
    int* col    = (int*)alloc((size_t)Etot * sizeof(int));
    (void)ws_size;

    float* F = (float*)d_out;  // feature ping-pong lives in d_out

    // ---- build combined CSR (by dst) for both edge sets ----
    const int nb = (Ntot + 1023) / 1024;  // 98 for N=50000
    hipMemsetAsync(cnt, 0, (size_t)Ntot * sizeof(int), stream);
    hist2_kernel<<<(Etot + 255) / 256, 256, 0, stream>>>(ei, eix, cnt, E1, E2, N);
    block_sum_kernel<<<nb, 1024, 0, stream>>>(cnt, bsum, Ntot);
    scan_bsums_kernel<<<1, 128, 0, stream>>>(bsum, nb, row, Ntot);
    block_scan_kernel<<<nb, 1024, 0, stream>>>(cnt, bsum, row, cur, Ntot);
    scatter2_kernel<<<(Etot + 255) / 256, 256, 0, stream>>>(ei, eix, cur, col, E1, E2, N);

    const int gemm_blocks = (N + 63) / 64;
    const int node_blocks = (N + 3) / 4;

    const float* cur_x = x;
    for (int L = 0; L < 5; ++L) {
        gemm128_fused<<<gemm_blocks, 256, 0, stream>>>(cur_x, W[L], asv[L], adv[L],
                                                       Hbuf, al, ar, N);
        const int* ro = row + ((L % 2 == 0) ? 0 : N);
        agg_kernel<<<node_blocks, 256, 0, stream>>>(Hbuf, al, ar, ro, col, bv[L], F, N,
                                                    (L < 4) ? 1 : 0);
        cur_x = F;
    }
}

// Round 4
// 638.502 us; speedup vs baseline: 1.2181x; 1.2181x over previous
//
#include <hip/hip_runtime.h>

#define DIM 128
#define NEG 0.2f
#define CAP 128    // per-node LDS alpha slots in agg
#define BSZ 512    // dst nodes per CSR bucket (dlow = 9 bits)
#define CB  256    // edge chunks for CSR partition

__device__ __forceinline__ float lrelu(float v) { return v > 0.f ? v : NEG * v; }

// ------------- GEMM + fused attention logits: H = X@W, al = H@a_src, ar = H@a_dst
__global__ __launch_bounds__(256) void gemm128_fused(const float* __restrict__ X,
                                                     const float* __restrict__ W,
                                                     const float* __restrict__ asrc,
                                                     const float* __restrict__ adst,
                                                     float* __restrict__ H,
                                                     float* __restrict__ al,
                                                     float* __restrict__ ar, int N) {
    __shared__ float sx[64 * 128];
    const int t = threadIdx.x;
    const int r0g = blockIdx.x * 64;
    const int remRows = N - r0g;

    const float4* X4 = (const float4*)(X + (size_t)r0g * DIM);
    float4* sx4 = (float4*)sx;
#pragma unroll
    for (int i = 0; i < 8; ++i) {
        int f = t + i * 256;
        int row = f >> 5;
        float4 v = make_float4(0.f, 0.f, 0.f, 0.f);
        if (row < remRows) v = X4[f];
        sx4[f] = v;
    }
    __syncthreads();

    const int c0 = (t & 31) * 4;
    const int rg = (t >> 5) * 8;
    float acc[8][4];
#pragma unroll
    for (int i = 0; i < 8; ++i)
#pragma unroll
        for (int j = 0; j < 4; ++j) acc[i][j] = 0.f;

    const float* Wp = W + c0;
    for (int k = 0; k < 128; k += 4) {
        float4 w0 = *(const float4*)(Wp + (k + 0) * DIM);
        float4 w1 = *(const float4*)(Wp + (k + 1) * DIM);
        float4 w2 = *(const float4*)(Wp + (k + 2) * DIM);
        float4 w3 = *(const float4*)(Wp + (k + 3) * DIM);
#pragma unroll
        for (int i = 0; i < 8; ++i) {
            float4 a = *(const float4*)(sx + (rg + i) * 128 + k);
            acc[i][0] += a.x * w0.x; acc[i][1] += a.x * w0.y; acc[i][2] += a.x * w0.z; acc[i][3] += a.x * w0.w;
            acc[i][0] += a.y * w1.x; acc[i][1] += a.y * w1.y; acc[i][2] += a.y * w1.z; acc[i][3] += a.y * w1.w;
            acc[i][0] += a.z * w2.x; acc[i][1] += a.z * w2.y; acc[i][2] += a.z * w2.z; acc[i][3] += a.z * w2.w;
            acc[i][0] += a.w * w3.x; acc[i][1] += a.w * w3.y; acc[i][2] += a.w * w3.z; acc[i][3] += a.w * w3.w;
        }
    }

#pragma unroll
    for (int i = 0; i < 8; ++i) {
        int row = rg + i;
        if (row < remRows) {
            float4 o = make_float4(acc[i][0], acc[i][1], acc[i][2], acc[i][3]);
            *(float4*)(H + (size_t)(r0g + row) * DIM + c0) = o;
        }
    }

    // fused epilogue: al/ar via half-wave reduction
    float4 av = *(const float4*)(asrc + c0);
    float4 dv = *(const float4*)(adst + c0);
    float pa[8], pr[8];
#pragma unroll
    for (int i = 0; i < 8; ++i) {
        pa[i] = acc[i][0] * av.x + acc[i][1] * av.y + acc[i][2] * av.z + acc[i][3] * av.w;
        pr[i] = acc[i][0] * dv.x + acc[i][1] * dv.y + acc[i][2] * dv.z + acc[i][3] * dv.w;
    }
#pragma unroll
    for (int off = 16; off; off >>= 1) {
#pragma unroll
        for (int i = 0; i < 8; ++i) {
            pa[i] += __shfl_xor(pa[i], off);
            pr[i] += __shfl_xor(pr[i], off);
        }
    }
    if ((t & 31) == 0) {
#pragma unroll
        for (int i = 0; i < 8; ++i) {
            int row = rg + i;
            if (row < remRows) {
                al[r0g + row] = pa[i];
                ar[r0g + row] = pr[i];
            }
        }
    }
}

// ================= CSR build: two-level counting sort, zero global atomics ===
// virtual dst d in [0, Ntot=2N): layer-even edges use d=dst, layer-odd d=N+dst.
// bucket b = d >> 9 (BSZ=512 nodes); NB buckets. CB edge chunks.

__device__ __forceinline__ void edge_decode(int e, const int* ei, const int* eix,
                                            int E1, int N, int E2, int& src, int& d) {
    if (e < E1) {
        src = ei[e];
        d = ei[E1 + e];
    } else {
        int k = e - E1;
        src = eix[k];
        d = N + eix[E2 + k];
    }
}

// P1: per-chunk histogram over buckets -> g_hist[b*CB + c]
__global__ __launch_bounds__(256) void csr_hist(const int* __restrict__ ei,
                                                const int* __restrict__ eix,
                                                int* __restrict__ g_hist,
                                                int E1, int E2, int N, int NB, int CE) {
    __shared__ int h[256];
    const int t = threadIdx.x;
    const int c = blockIdx.x;
    h[t] = 0;
    __syncthreads();
    const int Etot = E1 + E2;
    const int beg = c * CE;
    const int end = min(Etot, beg + CE);
    for (int e = beg + t; e < end; e += 256) {
        int src, d;
        edge_decode(e, ei, eix, E1, N, E2, src, d);
        atomicAdd(&h[d >> 9], 1);
    }
    __syncthreads();
    if (t < NB) g_hist[t * CB + c] = h[t];
}

// generic hierarchical exclusive scan over L ints --------------------------
__global__ __launch_bounds__(1024) void bsum_kernel(const int* __restrict__ in,
                                                    int* __restrict__ bsum, int L) {
    __shared__ int wsum[16];
    int t = threadIdx.x, wave = t >> 6, lane = t & 63;
    int i = blockIdx.x * 1024 + t;
    int v = (i < L) ? in[i] : 0;
#pragma unroll
    for (int off = 32; off; off >>= 1) v += __shfl_xor(v, off);
    if (lane == 0) wsum[wave] = v;
    __syncthreads();
    if (t == 0) {
        int s = 0;
#pragma unroll
        for (int j = 0; j < 16; ++j) s += wsum[j];
        bsum[blockIdx.x] = s;
    }
}

__global__ __launch_bounds__(128) void scan_small(int* __restrict__ bsum, int nb) {
    __shared__ int w0tot;
    int t = threadIdx.x;
    int v = (t < nb) ? bsum[t] : 0;
    int s = v;
#pragma unroll
    for (int off = 1; off < 64; off <<= 1) {
        int u = __shfl_up(s, off);
        if ((t & 63) >= off) s += u;
    }
    if (t == 63) w0tot = s;
    __syncthreads();
    if (t >= 64) s += w0tot;
    if (t < nb) bsum[t] = s - v;  // exclusive
}

__global__ __launch_bounds__(1024) void bscan_kernel(const int* __restrict__ in,
                                                     const int* __restrict__ bsum,
                                                     int* __restrict__ out, int L) {
    __shared__ int wsum[16];
    __shared__ int woff[16];
    int t = threadIdx.x, wave = t >> 6, lane = t & 63;
    int i = blockIdx.x * 1024 + t;
    int v = (i < L) ? in[i] : 0;
    int s = v;
#pragma unroll
    for (int off = 1; off < 64; off <<= 1) {
        int u = __shfl_up(s, off);
        if (lane >= off) s += u;
    }
    if (lane == 63) wsum[wave] = s;
    __syncthreads();
    if (t == 0) {
        int r = 0;
#pragma unroll
        for (int j = 0; j < 16; ++j) { woff[j] = r; r += wsum[j]; }
    }
    __syncthreads();
    if (i < L) out[i] = bsum[blockIdx.x] + woff[wave] + s - v;
}

// P3: partition edges into bucket-contiguous staging, packed (dlow<<22)|src
__global__ __launch_bounds__(256) void csr_partition(const int* __restrict__ ei,
                                                     const int* __restrict__ eix,
                                                     const int* __restrict__ g_base,
                                                     unsigned* __restrict__ staging,
                                                     int E1, int E2, int N, int NB, int CE) {
    __shared__ int cur[256];
    const int t = threadIdx.x;
    const int c = blockIdx.x;
    if (t < NB) cur[t] = g_base[t * CB + c];
    __syncthreads();
    const int Etot = E1 + E2;
    const int beg = c * CE;
    const int end = min(Etot, beg + CE);
    for (int e = beg + t; e < end; e += 256) {
        int src, d;
        edge_decode(e, ei, eix, E1, N, E2, src, d);
        int p = atomicAdd(&cur[d >> 9], 1);
        staging[p] = ((unsigned)(d & (BSZ - 1)) << 22) | (unsigned)src;
    }
}

// P4: per-bucket finalize: row_off + windowed col scatter (LDS cursors only)
__global__ __launch_bounds__(256) void csr_finalize(const unsigned* __restrict__ staging,
                                                    const int* __restrict__ g_base,
                                                    int* __restrict__ row_off,
                                                    int* __restrict__ col,
                                                    int Ntot, int Etot, int NB) {
    __shared__ int cnt_s[BSZ];
    __shared__ int cur_s[BSZ];
    __shared__ int wsum[4], woff[4];
    const int t = threadIdx.x;      // 256
    const int k = blockIdx.x;       // bucket
    cnt_s[t] = 0;
    cnt_s[t + 256] = 0;
    __syncthreads();
    const int seg_beg = g_base[k * CB];
    const int seg_end = (k == NB - 1) ? Etot : g_base[(k + 1) * CB];
    for (int i = seg_beg + t; i < seg_end; i += 256)
        atomicAdd(&cnt_s[staging[i] >> 22], 1);
    __syncthreads();

    // block exclusive scan of cnt_s[512]: 2 elems/thread
    const int a = cnt_s[2 * t], b = cnt_s[2 * t + 1];
    const int tsum = a + b;
    int s = tsum;
    const int lane = t & 63, wv = t >> 6;
#pragma unroll
    for (int off = 1; off < 64; off <<= 1) {
        int u = __shfl_up(s, off);
        if (lane >= off) s += u;
    }
    if (lane == 63) wsum[wv] = s;
    __syncthreads();
    if (t == 0) {
        int r = 0;
#pragma unroll
        for (int j = 0; j < 4; ++j) { woff[j] = r; r += wsum[j]; }
    }
    __syncthreads();
    const int excl = woff[wv] + s - tsum;  // exclusive start for elem 2t
    cur_s[2 * t] = seg_beg + excl;
    cur_s[2 * t + 1] = seg_beg + excl + a;
    const int nbase = k * BSZ;
    if (nbase + 2 * t < Ntot)     row_off[nbase + 2 * t]     = seg_beg + excl;
    if (nbase + 2 * t + 1 < Ntot) row_off[nbase + 2 * t + 1] = seg_beg + excl + a;
    __syncthreads();
    for (int i = seg_beg + t; i < seg_end; i += 256) {
        unsigned v = staging[i];
        int p = atomicAdd(&cur_s[v >> 22], 1);
        col[p] = (int)(v & 0x3FFFFFu);
    }
    if (k == 0 && t == 0) row_off[Ntot] = Etot;
}

// ---------------- fused softmax-by-dst + aggregation, one wave per node -----
__global__ __launch_bounds__(256) void agg_kernel(const float* __restrict__ H,
                                                  const float* __restrict__ al,
                                                  const float* __restrict__ ar,
                                                  const int* __restrict__ row_off,
                                                  const int* __restrict__ col,
                                                  const float* __restrict__ bias,
                                                  float* __restrict__ out, int N, int relu) {
    __shared__ float salpha[4][CAP];
    const int wv = threadIdx.x >> 6;
    const int w = blockIdx.x * 4 + wv;
    const int lane = threadIdx.x & 63;
    if (w >= N) return;

    const int beg = row_off[w];
    const int deg = row_off[w + 1] - beg;
    const float arn = ar[w];
    const float vself = lrelu(al[w] + arn);

    // phase A: online segment softmax, logits -> LDS
    float mm = -1e30f, ss = 0.f;
    for (int i = lane; i < deg; i += 64) {
        float v = lrelu(al[col[beg + i]] + arn);
        if (i < CAP) salpha[wv][i] = v;
        float nm = fmaxf(mm, v);
        ss = ss * __expf(mm - nm) + __expf(v - nm);
        mm = nm;
    }
#pragma unroll
    for (int off = 32; off; off >>= 1) {
        float mo = __shfl_xor(mm, off);
        float so = __shfl_xor(ss, off);
        float nm = fmaxf(mm, mo);
        ss = ss * __expf(mm - nm) + so * __expf(mo - nm);
        mm = nm;
    }
    {
        float nm = fmaxf(mm, vself);
        ss = ss * __expf(mm - nm) + __expf(vself - nm);
        mm = nm;
    }
    const float m = mm;
    const float invs = 1.f / ss;

    const int capdeg = deg < CAP ? deg : CAP;
    for (int i = lane; i < capdeg; i += 64)
        salpha[wv][i] = __expf(salpha[wv][i] - m) * invs;

    // phase B: weighted aggregation, 2 half-waves x unroll 4
    const int half = lane >> 5;
    const int l32 = lane & 31;
    const float aself = __expf(vself - m) * invs;
    const float4 hs = *(const float4*)(H + (size_t)w * DIM + 4 * l32);
    float4 acc = make_float4(0.f, 0.f, 0.f, 0.f);
    if (half == 0) {
        acc.x = aself * hs.x; acc.y = aself * hs.y;
        acc.z = aself * hs.z; acc.w = aself * hs.w;
    }

    int i = half;
    for (; i + 6 < deg; i += 8) {
        const int e = beg + i;
        int sn0 = col[e];
        int sn1 = col[e + 2];
        int sn2 = col[e + 4];
        int sn3 = col[e + 6];
        float a0, a1, a2, a3;
        if (i + 6 < CAP) {
            a0 = salpha[wv][i];     a1 = salpha[wv][i + 2];
            a2 = salpha[wv][i + 4]; a3 = salpha[wv][i + 6];
        } else {
            a0 = __expf(lrelu(al[sn0] + arn) - m) * invs;
            a1 = __expf(lrelu(al[sn1] + arn) - m) * invs;
            a2 = __expf(lrelu(al[sn2] + arn) - m) * invs;
            a3 = __expf(lrelu(al[sn3] + arn) - m) * invs;
        }
        const float4 h0 = *(const float4*)(H + (size_t)sn0 * DIM + 4 * l32);
        const float4 h1 = *(const float4*)(H + (size_t)sn1 * DIM + 4 * l32);
        const float4 h2 = *(const float4*)(H + (size_t)sn2 * DIM + 4 * l32);
        const float4 h3 = *(const float4*)(H + (size_t)sn3 * DIM + 4 * l32);
        acc.x += a0 * h0.x + a1 * h1.x + a2 * h2.x + a3 * h3.x;
        acc.y += a0 * h0.y + a1 * h1.y + a2 * h2.y + a3 * h3.y;
        acc.z += a0 * h0.z + a1 * h1.z + a2 * h2.z + a3 * h3.z;
        acc.w += a0 * h0.w + a1 * h1.w + a2 * h2.w + a3 * h3.w;
    }
    for (; i < deg; i += 2) {
        int sn = col[beg + i];
        float a = (i < CAP) ? salpha[wv][i]
                            : __expf(lrelu(al[sn] + arn) - m) * invs;
        const float4 hv = *(const float4*)(H + (size_t)sn * DIM + 4 * l32);
        acc.x += a * hv.x; acc.y += a * hv.y;
        acc.z += a * hv.z; acc.w += a * hv.w;
    }

    acc.x += __shfl_xor(acc.x, 32);
    acc.y += __shfl_xor(acc.y, 32);
    acc.z += __shfl_xor(acc.z, 32);
    acc.w += __shfl_xor(acc.w, 32);

    if (half == 0) {
        float4 b = *(const float4*)(bias + 4 * l32);
        float4 o = make_float4(acc.x + b.x, acc.y + b.y, acc.z + b.z, acc.w + b.w);
        if (relu) {
            o.x = fmaxf(o.x, 0.f); o.y = fmaxf(o.y, 0.f);
            o.z = fmaxf(o.z, 0.f); o.w = fmaxf(o.w, 0.f);
        }
        *(float4*)(out + (size_t)w * DIM + 4 * l32) = o;
    }
}

// ---------------- host-side launch ----------------
extern "C" void kernel_launch(void* const* d_in, const int* in_sizes, int n_in,
                              void* d_out, int out_size, void* d_ws, size_t ws_size,
                              hipStream_t stream) {
    const float* x = (const float*)d_in[0];
    const float* W[5];
    const float* asv[5];
    const float* adv[5];
    const float* bv[5];
    for (int i = 0; i < 5; ++i) {
        W[i]   = (const float*)d_in[1 + 4 * i];
        asv[i] = (const float*)d_in[2 + 4 * i];
        adv[i] = (const float*)d_in[3 + 4 * i];
        bv[i]  = (const float*)d_in[4 + 4 * i];
    }
    const int* ei  = (const int*)d_in[21];
    const int* eix = (const int*)d_in[22];
    const int N  = in_sizes[0] / DIM;
    const int E1 = in_sizes[21] / 2;
    const int E2 = in_sizes[22] / 2;
    const int Ntot = 2 * N;
    const int Etot = E1 + E2;
    const int NB = (Ntot + BSZ - 1) / BSZ;       // 196 for N=50000 (<=256 required)
    const int CE = (Etot + CB - 1) / CB;

    size_t off = 0;
    auto alloc = [&](size_t bytes) {
        void* r = (char*)d_ws + off;
        off += (bytes + 255) & ~(size_t)255;
        return r;
    };
    float* Hbuf  = (float*)alloc((size_t)N * DIM * sizeof(float));
    float* al    = (float*)alloc((size_t)N * sizeof(float));
    float* ar    = (float*)alloc((size_t)N * sizeof(float));
    int* g_hist  = (int*)alloc((size_t)NB * CB * sizeof(int));
    int* g_base  = (int*)alloc((size_t)NB * CB * sizeof(int));
    int* bsum    = (int*)alloc(128 * sizeof(int));
    int* row     = (int*)alloc((size_t)(Ntot + 1) * sizeof(int));
    int* col     = (int*)alloc((size_t)Etot * sizeof(int));
    (void)ws_size;
    // staging aliases Hbuf: CSR build finishes before the first gemm writes H
    unsigned* staging = (unsigned*)Hbuf;

    float* F = (float*)d_out;  // feature ping-pong lives in d_out

    // ---- CSR build (combined 2N-node graph), no global atomics ----
    const int L = NB * CB;
    const int nbb = (L + 1023) / 1024;           // 49 (<=128 required)
    csr_hist<<<CB, 256, 0, stream>>>(ei, eix, g_hist, E1, E2, N, NB, CE);
    bsum_kernel<<<nbb, 1024, 0, stream>>>(g_hist, bsum, L);
    scan_small<<<1, 128, 0, stream>>>(bsum, nbb);
    bscan_kernel<<<nbb, 1024, 0, stream>>>(g_hist, bsum, g_base, L);
    csr_partition<<<CB, 256, 0, stream>>>(ei, eix, g_base, staging, E1, E2, N, NB, CE);
    csr_finalize<<<NB, 256, 0, stream>>>(staging, g_base, row, col, Ntot, Etot, NB);

    const int gemm_blocks = (N + 63) / 64;
    const int node_blocks = (N + 3) / 4;

    const float* cur_x = x;
    for (int Lyr = 0; Lyr < 5; ++Lyr) {
        gemm128_fused<<<gemm_blocks, 256, 0, stream>>>(cur_x, W[Lyr], asv[Lyr], adv[Lyr],
                                                       Hbuf, al, ar, N);
        const int* ro = row + ((Lyr % 2 == 0) ? 0 : N);
        agg_kernel<<<node_blocks, 256, 0, stream>>>(Hbuf, al, ar, ro, col, bv[Lyr], F, N,
                                                    (Lyr < 4) ? 1 : 0);
        cur_x = F;
    }
}